// Round 5
// baseline (53.802 us; speedup 1.0000x reference)
//
#include <hip/hip_runtime.h>

// HeadDetectorLoss: scalar loss over N rows (N=4194304).
//   prediction (N,6) f32: [:,0:2]=class logits, [:,2:6]=box pred
//   target_class (N,) i32 in {0,1}; target_box (N,4) f32
//   out = mean(nll) + 10 * sum(mse*mask) / (1e-6 + sum(mask))
// Memory-bound streaming reduction: 184.5 MB read, 4 B written.
//
// History:
//  R1/R4 two-kernel: wall 36.9/35.3 us, reduce ~5.9 TB/s (VGPR 20).
//  R2/R3 fused w/ __threadfence + acq-rel per block: 4.5x regression --
//    threadfence@agent = buffer_wbl2+inv per block, ~185 us serialized at TCC.
//  This round: fused finalize, FENCE-FREE -- relaxed sc1 atomics (coherent at
//    L3/mall, the device coherence point) + explicit s_waitcnt vmcnt(0) to
//    order partial-stores before the counter add. Deterministic: fixed-order
//    final summation; which block runs it doesn't affect the value.

#define GRID 2048
#define BLOCK 256

__global__ __launch_bounds__(BLOCK) void hdl_fused(
    const float* __restrict__ pred,
    const int*   __restrict__ tcls,
    const float* __restrict__ tbox,
    float* __restrict__ part,           // [3*GRID] SoA partials: nll | box | cnt
    unsigned int* __restrict__ counter, // zeroed by memset node each call
    float* __restrict__ out,
    int nrows)
{
  const int tid    = blockIdx.x * BLOCK + threadIdx.x;
  const int stride = GRID * BLOCK;
  const int npairs = nrows >> 1;           // 2 rows/thread-iter for float4 alignment

  float nll = 0.f, box = 0.f, cnt = 0.f;

  for (long long t = tid; t < npairs; t += stride) {
    // pair t = rows 2t, 2t+1: pred floats [12t, 12t+12), 48-byte aligned
    const float4 q0 = *reinterpret_cast<const float4*>(pred + 12ll * t);      // r0: l0 l1 b0 b1
    const float4 q1 = *reinterpret_cast<const float4*>(pred + 12ll * t + 4);  // r0: b2 b3 | r1: l0 l1
    const float4 q2 = *reinterpret_cast<const float4*>(pred + 12ll * t + 8);  // r1: b0 b1 b2 b3
    const float4 b0 = *reinterpret_cast<const float4*>(tbox + 8ll * t);
    const float4 b1 = *reinterpret_cast<const float4*>(tbox + 8ll * t + 4);
    const int2   c  = *reinterpret_cast<const int2*>(tcls + 2ll * t);

    { // row 0
      float m   = fmaxf(q0.x, q0.y);
      float lse = m + __logf(__expf(q0.x - m) + __expf(q0.y - m));
      nll += lse - (c.x == 0 ? q0.x : q0.y);
      float d0 = q0.z - b0.x, d1 = q0.w - b0.y, d2 = q1.x - b0.z, d3 = q1.y - b0.w;
      float mse = 0.25f * (d0*d0 + d1*d1 + d2*d2 + d3*d3);
      if (c.x != 0) { box += mse; cnt += 1.f; }
    }
    { // row 1
      float m   = fmaxf(q1.z, q1.w);
      float lse = m + __logf(__expf(q1.z - m) + __expf(q1.w - m));
      nll += lse - (c.y == 0 ? q1.z : q1.w);
      float d0 = q2.x - b1.x, d1 = q2.y - b1.y, d2 = q2.z - b1.z, d3 = q2.w - b1.w;
      float mse = 0.25f * (d0*d0 + d1*d1 + d2*d2 + d3*d3);
      if (c.y != 0) { box += mse; cnt += 1.f; }
    }
  }
  // Odd-row tail (none at N=4194304).
  if (tid == 0 && (nrows & 1)) {
    const long long r = nrows - 1;
    float l0 = pred[6*r], l1 = pred[6*r+1];
    float m = fmaxf(l0, l1);
    float lse = m + __logf(__expf(l0 - m) + __expf(l1 - m));
    int ci = tcls[r];
    nll += lse - (ci == 0 ? l0 : l1);
    float d0 = pred[6*r+2] - tbox[4*r+0], d1 = pred[6*r+3] - tbox[4*r+1];
    float d2 = pred[6*r+4] - tbox[4*r+2], d3 = pred[6*r+5] - tbox[4*r+3];
    float mse = 0.25f * (d0*d0 + d1*d1 + d2*d2 + d3*d3);
    if (ci != 0) { box += mse; cnt += 1.f; }
  }

  // wave64 tree reduction
  #pragma unroll
  for (int off = 32; off > 0; off >>= 1) {
    nll += __shfl_down(nll, off);
    box += __shfl_down(box, off);
    cnt += __shfl_down(cnt, off);
  }

  __shared__ float s[3][BLOCK / 64];
  __shared__ bool  lastBlock;
  const int lane = threadIdx.x & 63, w = threadIdx.x >> 6;
  if (lane == 0) { s[0][w] = nll; s[1][w] = box; s[2][w] = cnt; }
  __syncthreads();
  if (threadIdx.x == 0) {
    float a = 0.f, b = 0.f, cn = 0.f;
    #pragma unroll
    for (int i = 0; i < BLOCK / 64; ++i) { a += s[0][i]; b += s[1][i]; cn += s[2][i]; }
    // sc1 atomic stores: visible at the device coherence point (L3/mall),
    // no L2 writeback needed. SoA layout -> coalesced finalize reads.
    __hip_atomic_store(&part[blockIdx.x],            a,  __ATOMIC_RELAXED, __HIP_MEMORY_SCOPE_AGENT);
    __hip_atomic_store(&part[GRID + blockIdx.x],     b,  __ATOMIC_RELAXED, __HIP_MEMORY_SCOPE_AGENT);
    __hip_atomic_store(&part[2 * GRID + blockIdx.x], cn, __ATOMIC_RELAXED, __HIP_MEMORY_SCOPE_AGENT);
    // Order: partial stores must complete (at coherence point) before the
    // counter increment. NO cache flush -- just drain vmem.
    asm volatile("s_waitcnt vmcnt(0)" ::: "memory");
    unsigned prev = __hip_atomic_fetch_add(counter, 1u, __ATOMIC_RELAXED, __HIP_MEMORY_SCOPE_AGENT);
    lastBlock = (prev == GRID - 1);
  }
  __syncthreads();

  if (lastBlock) {
    // Fixed-order summation -> deterministic result regardless of which
    // block executes this.
    float A = 0.f, B = 0.f, C = 0.f;
    for (int i = threadIdx.x; i < GRID; i += BLOCK) {
      A += __hip_atomic_load(&part[i],            __ATOMIC_RELAXED, __HIP_MEMORY_SCOPE_AGENT);
      B += __hip_atomic_load(&part[GRID + i],     __ATOMIC_RELAXED, __HIP_MEMORY_SCOPE_AGENT);
      C += __hip_atomic_load(&part[2 * GRID + i], __ATOMIC_RELAXED, __HIP_MEMORY_SCOPE_AGENT);
    }
    #pragma unroll
    for (int off = 32; off > 0; off >>= 1) {
      A += __shfl_down(A, off);
      B += __shfl_down(B, off);
      C += __shfl_down(C, off);
    }
    __syncthreads();   // s[] reuse
    if (lane == 0) { s[0][w] = A; s[1][w] = B; s[2][w] = C; }
    __syncthreads();
    if (threadIdx.x == 0) {
      float sa = 0.f, sb = 0.f, sc = 0.f;
      #pragma unroll
      for (int i = 0; i < BLOCK / 64; ++i) { sa += s[0][i]; sb += s[1][i]; sc += s[2][i]; }
      out[0] = sa / (float)nrows + 10.0f * sb / (1e-6f + sc);
    }
  }
}

extern "C" void kernel_launch(void* const* d_in, const int* in_sizes, int n_in,
                              void* d_out, int out_size, void* d_ws, size_t ws_size,
                              hipStream_t stream) {
  const float* pred = (const float*)d_in[0];
  const int*   tcls = (const int*)d_in[1];
  const float* tbox = (const float*)d_in[2];
  float* out  = (float*)d_out;
  float* part = (float*)d_ws;                               // 3*GRID floats = 24 KB
  unsigned int* counter = (unsigned int*)((char*)d_ws + 3 * GRID * sizeof(float));
  const int nrows = in_sizes[1];                            // N from target_class

  hipMemsetAsync(counter, 0, sizeof(unsigned int), stream); // reset finalize counter
  hdl_fused<<<GRID, BLOCK, 0, stream>>>(pred, tcls, tbox, part, counter, out, nrows);
}

// Round 6
// 35.175 us; speedup vs baseline: 1.5295x; 1.5295x over previous
//
#include <hip/hip_runtime.h>

// HeadDetectorLoss: scalar loss over N rows (N=4194304).
//   prediction (N,6) f32: [:,0:2]=class logits, [:,2:6]=box pred
//   target_class (N,) i32 in {0,1}; target_box (N,4) f32
//   out = mean(nll) + 10 * sum(mse*mask) / (1e-6 + sum(mask))
// Memory-bound streaming reduction: 184.5 MB read, 4 B written.
//
// History:
//  R1/R4 two-kernel, simple loop: wall 36.9/35.3 us (reduce ~5.8 TB/s, VGPR 20
//    -> compiler waits vmcnt mid-iteration, zero per-thread MLP).
//  R2/R3 fused + __threadfence: 4.5x regression (L2 wb/inv per block).
//  R5 fused fence-free: still +18 us (tail-serialized same-address atomics +
//    last-block finalize cost more than the 2nd launch saves). Fusion dead end.
//  R6 (this): two-kernel + 2-deep software pipeline in the reduce loop --
//    issue next iteration's 6 loads before consuming current. Named float4
//    locals only (no aggregates / conditional init -> stays in registers).

#define GRID 2048
#define BLOCK 256

__device__ __forceinline__ void pair_acc(
    const float4 q0, const float4 q1, const float4 q2,
    const float4 b0, const float4 b1, const int2 c,
    float& nll, float& box, float& cnt)
{
  { // row 0: logits q0.x q0.y, box pred q0.z q0.w q1.x q1.y
    float m   = fmaxf(q0.x, q0.y);
    float lse = m + __logf(__expf(q0.x - m) + __expf(q0.y - m));
    nll += lse - (c.x == 0 ? q0.x : q0.y);
    float d0 = q0.z - b0.x, d1 = q0.w - b0.y, d2 = q1.x - b0.z, d3 = q1.y - b0.w;
    float mse = 0.25f * (d0*d0 + d1*d1 + d2*d2 + d3*d3);
    if (c.x != 0) { box += mse; cnt += 1.f; }
  }
  { // row 1: logits q1.z q1.w, box pred q2
    float m   = fmaxf(q1.z, q1.w);
    float lse = m + __logf(__expf(q1.z - m) + __expf(q1.w - m));
    nll += lse - (c.y == 0 ? q1.z : q1.w);
    float d0 = q2.x - b1.x, d1 = q2.y - b1.y, d2 = q2.z - b1.z, d3 = q2.w - b1.w;
    float mse = 0.25f * (d0*d0 + d1*d1 + d2*d2 + d3*d3);
    if (c.y != 0) { box += mse; cnt += 1.f; }
  }
}

__global__ __launch_bounds__(BLOCK) void hdl_reduce(
    const float* __restrict__ pred,
    const int*   __restrict__ tcls,
    const float* __restrict__ tbox,
    float* __restrict__ part,   // [3*GRID] partials: nll | box | cnt (SoA)
    int nrows)
{
  const int tid    = blockIdx.x * BLOCK + threadIdx.x;
  const int stride = GRID * BLOCK;
  const long long npairs = nrows >> 1;   // 2 rows per pair (float4-aligned)

  float nll = 0.f, box = 0.f, cnt = 0.f;

  long long t = tid;
  if (t < npairs) {
    // Prologue: load current pair.
    float4 q0 = *reinterpret_cast<const float4*>(pred + 12 * t);
    float4 q1 = *reinterpret_cast<const float4*>(pred + 12 * t + 4);
    float4 q2 = *reinterpret_cast<const float4*>(pred + 12 * t + 8);
    float4 b0 = *reinterpret_cast<const float4*>(tbox + 8 * t);
    float4 b1 = *reinterpret_cast<const float4*>(tbox + 8 * t + 4);
    int2   c  = *reinterpret_cast<const int2*>(tcls + 2 * t);

    // Steady state: issue next pair's loads, then consume current.
    for (; t + stride < npairs; t += stride) {
      const long long tn = t + stride;
      const float4 n0 = *reinterpret_cast<const float4*>(pred + 12 * tn);
      const float4 n1 = *reinterpret_cast<const float4*>(pred + 12 * tn + 4);
      const float4 n2 = *reinterpret_cast<const float4*>(pred + 12 * tn + 8);
      const float4 m0 = *reinterpret_cast<const float4*>(tbox + 8 * tn);
      const float4 m1 = *reinterpret_cast<const float4*>(tbox + 8 * tn + 4);
      const int2   nc = *reinterpret_cast<const int2*>(tcls + 2 * tn);

      pair_acc(q0, q1, q2, b0, b1, c, nll, box, cnt);

      q0 = n0; q1 = n1; q2 = n2; b0 = m0; b1 = m1; c = nc;
    }
    // Epilogue: consume last pair.
    pair_acc(q0, q1, q2, b0, b1, c, nll, box, cnt);
  }
  // Odd-row tail (none at N=4194304).
  if (tid == 0 && (nrows & 1)) {
    const long long r = nrows - 1;
    float l0 = pred[6*r], l1 = pred[6*r+1];
    float m = fmaxf(l0, l1);
    float lse = m + __logf(__expf(l0 - m) + __expf(l1 - m));
    int ci = tcls[r];
    nll += lse - (ci == 0 ? l0 : l1);
    float d0 = pred[6*r+2] - tbox[4*r+0], d1 = pred[6*r+3] - tbox[4*r+1];
    float d2 = pred[6*r+4] - tbox[4*r+2], d3 = pred[6*r+5] - tbox[4*r+3];
    float mse = 0.25f * (d0*d0 + d1*d1 + d2*d2 + d3*d3);
    if (ci != 0) { box += mse; cnt += 1.f; }
  }

  // wave64 tree reduction
  #pragma unroll
  for (int off = 32; off > 0; off >>= 1) {
    nll += __shfl_down(nll, off);
    box += __shfl_down(box, off);
    cnt += __shfl_down(cnt, off);
  }

  __shared__ float s[3][BLOCK / 64];
  const int lane = threadIdx.x & 63, w = threadIdx.x >> 6;
  if (lane == 0) { s[0][w] = nll; s[1][w] = box; s[2][w] = cnt; }
  __syncthreads();
  if (threadIdx.x == 0) {
    float a = 0.f, b = 0.f, cn = 0.f;
    #pragma unroll
    for (int i = 0; i < BLOCK / 64; ++i) { a += s[0][i]; b += s[1][i]; cn += s[2][i]; }
    part[blockIdx.x]            = a;
    part[GRID + blockIdx.x]     = b;
    part[2 * GRID + blockIdx.x] = cn;
  }
}

// Finalize: 1 block x 1024 threads, float4 reads -> one latency round.
// part as float4: f4[0..512)=nll, f4[512..1024)=box, f4[1024..1536)=cnt.
__global__ __launch_bounds__(1024) void hdl_final(
    const float* __restrict__ part, float* __restrict__ out, int nrows)
{
  const int t = threadIdx.x;
  const float4* p4 = reinterpret_cast<const float4*>(part);

  float a = 0.f, b = 0.f, c = 0.f;
  if (t < 512) {
    const float4 q = p4[t];          // nll chunk
    const float4 r = p4[1024 + t];   // cnt chunk
    a = (q.x + q.y) + (q.z + q.w);
    c = (r.x + r.y) + (r.z + r.w);
  } else {
    const float4 q = p4[t];          // box chunk
    b = (q.x + q.y) + (q.z + q.w);
  }

  #pragma unroll
  for (int off = 32; off > 0; off >>= 1) {
    a += __shfl_down(a, off);
    b += __shfl_down(b, off);
    c += __shfl_down(c, off);
  }

  __shared__ float s[3][16];
  const int lane = t & 63, w = t >> 6;   // 16 waves
  if (lane == 0) { s[0][w] = a; s[1][w] = b; s[2][w] = c; }
  __syncthreads();
  if (t == 0) {
    float A = 0.f, B = 0.f, C = 0.f;
    #pragma unroll
    for (int i = 0; i < 16; ++i) { A += s[0][i]; B += s[1][i]; C += s[2][i]; }
    out[0] = A / (float)nrows + 10.0f * B / (1e-6f + C);
  }
}

extern "C" void kernel_launch(void* const* d_in, const int* in_sizes, int n_in,
                              void* d_out, int out_size, void* d_ws, size_t ws_size,
                              hipStream_t stream) {
  const float* pred = (const float*)d_in[0];
  const int*   tcls = (const int*)d_in[1];
  const float* tbox = (const float*)d_in[2];
  float* out  = (float*)d_out;
  float* part = (float*)d_ws;           // 3*GRID floats = 24 KB
  const int nrows = in_sizes[1];        // N from target_class

  hdl_reduce<<<GRID, BLOCK, 0, stream>>>(pred, tcls, tbox, part, nrows);
  hdl_final<<<1, 1024, 0, stream>>>(part, out, nrows);
}